// Round 2
// 125.032 us; speedup vs baseline: 1.0771x; 1.0771x over previous
//
#include <hip/hip_runtime.h>
#include <cmath>

// PillarFeatureNet fused: augment(10ch) -> linear(64) -> BN(inference) -> exact GELU -> max over points.
// Key algebra: y[m][o] = f0*A0 + f1*A1 + f2*A2 + f3*A3 + C_pillar  (4 FMAs/point instead of 10 MACs)
//   A_i fold W columns + BN scale (pillar-independent, lane-resident);
//   C folds points_mean, voxel-center offsets, BN bias.
// GELU is valley-shaped => max_m gelu(y_m) = max(gelu(max_m y), gelu(min_m y)): 2 erfs per (n,o).
// Masked points (m >= num_points) contribute y = b (BN of 0), added once when num_points < 32.
// NOTE: points_mean sums ALL 32 rows (reference semantics), mask applies only to the matmul.
//
// R2 == R1 resubmit (R1 bench was a container-acquire failure, no kernel diagnostic):
//   - inner loop 2 points/iter with forced v_max3/v_min3 (halves minmax + loop overhead)
//   - points_mean via v_rcp_f32 + mul instead of 6 IEEE divides (~1e-7 rel err, ~50 VALU/pair saved)
//   - grid ~6250 blocks (2 pairs/wave) instead of 2048 (6 pairs/wave): HW backfill shrinks
//     the num_points-variance makespan tail (occupancy was 43% with VALUBusy 76%)

__device__ __forceinline__ float gelu_exact(float x) {
    return 0.5f * x * (1.0f + erff(x * 0.70710678118654752440f));
}

__device__ __forceinline__ float max3f(float a, float b, float c) {
    float d;
    asm("v_max3_f32 %0, %1, %2, %3" : "=v"(d) : "v"(a), "v"(b), "v"(c));
    return d;
}
__device__ __forceinline__ float min3f(float a, float b, float c) {
    float d;
    asm("v_min3_f32 %0, %1, %2, %3" : "=v"(d) : "v"(a), "v"(b), "v"(c));
    return d;
}

__global__ __launch_bounds__(256) void pfn_kernel(
    const float* __restrict__ features,   // (N, 32, 4)
    const int*   __restrict__ num_points, // (N,)
    const int*   __restrict__ coors,      // (N, 4)
    const float* __restrict__ W,          // (64, 10)
    const float* __restrict__ gamma,      // (64,)
    const float* __restrict__ beta,       // (64,)
    const float* __restrict__ rmean,      // (64,)
    const float* __restrict__ rvar,       // (64,)
    float*       __restrict__ out,        // (N, 64)
    int nTotal)
{
    __shared__ float4 lds[4][64];  // per-wave slot: [0..31] = pillar A points, [32..63] = pillar B

    const int lane = threadIdx.x & 63;
    const int wid  = threadIdx.x >> 6;
    const int waveGlobal = blockIdx.x * 4 + wid;
    const int waveCount  = gridDim.x * 4;
    const int nPairs = (nTotal + 1) >> 1;

    // lane == output channel o
    const int o = lane;
    const float w0 = W[o*10+0], w1 = W[o*10+1], w2 = W[o*10+2], w3 = W[o*10+3],
                w4 = W[o*10+4], w5 = W[o*10+5], w6 = W[o*10+6], w7 = W[o*10+7],
                w8 = W[o*10+8], w9 = W[o*10+9];
    const float a = gamma[o] / sqrtf(rvar[o] + 1e-3f);        // inv_std * gamma
    const float b = fmaf(-rmean[o], a, beta[o]);              // BN(0) value
    const float A0 = a*(w0+w4+w7), A1 = a*(w1+w5+w8), A2 = a*(w2+w6+w9), A3 = a*w3;

    for (int p = waveGlobal; p < nPairs; p += waveCount) {
        const int iA = 2*p;
        const bool hasB = (2*p + 1 < nTotal);
        const int iB = hasB ? (2*p + 1) : (nTotal - 1);

        // ---- phase 1: coalesced load of 2 pillars (1 KB contiguous), mean reduction ----
        const float4* fb = reinterpret_cast<const float4*>(features) + (size_t)p * 64;
        float4 f = fb[lane];          // lane l -> pillar (2p + (l>=32)), point (l&31)
        lds[wid][lane] = f;

        float sx = f.x, sy = f.y, sz = f.z;
        #pragma unroll
        for (int d = 1; d < 32; d <<= 1) {
            sx += __shfl_xor(sx, d);
            sy += __shfl_xor(sy, d);
            sz += __shfl_xor(sz, d);
        }
        const float tx = __shfl_xor(sx, 32), ty = __shfl_xor(sy, 32), tz = __shfl_xor(sz, 32);
        const bool lo = (lane < 32);
        const float sAx = lo ? sx : tx, sAy = lo ? sy : ty, sAz = lo ? sz : tz;
        const float sBx = lo ? tx : sx, sBy = lo ? ty : sy, sBz = lo ? tz : sz;

        const int nA = num_points[iA];
        const int nB = num_points[iB];
        const int4 cA = reinterpret_cast<const int4*>(coors)[iA];
        const int4 cB = reinterpret_cast<const int4*>(coors)[iB];

        // points_mean = sum(all 32) * rcp(num_points); v_rcp_f32 is <=1ulp (vs IEEE divide):
        // downstream error ~1e-6 absolute, well inside tolerance, saves ~50 VALU/pair.
        const float rcA = __builtin_amdgcn_rcpf((float)nA);
        const float rcB = __builtin_amdgcn_rcpf((float)nB);
        const float mAx = sAx * rcA, mAy = sAy * rcA, mAz = sAz * rcA;
        const float mBx = sBx * rcB, mBy = sBy * rcB, mBz = sBz * rcB;

        // voxel-center offsets: cx=coors[:,2], cy=coors[:,1], cz=coors[:,0]
        const float ccxA = fmaf((float)cA.z, 0.2f,   0.1f);
        const float ccyA = fmaf((float)cA.y, 0.2f, -39.9f);
        const float cczA = fmaf((float)cA.x, 4.0f,  -1.0f);
        const float ccxB = fmaf((float)cB.z, 0.2f,   0.1f);
        const float ccyB = fmaf((float)cB.y, 0.2f, -39.9f);
        const float cczB = fmaf((float)cB.x, 4.0f,  -1.0f);

        const float KA = -(mAx*w4 + mAy*w5 + mAz*w6 + ccxA*w7 + ccyA*w8 + cczA*w9);
        const float KB = -(mBx*w4 + mBy*w5 + mBz*w6 + ccxB*w7 + ccyB*w8 + cczB*w9);
        const float CA = fmaf(a, KA, b);
        const float CB = fmaf(a, KB, b);

        // intra-wave LDS RAW: DS ops are in-order per wave; fence the compiler + drain lgkm
        __asm__ volatile("s_waitcnt lgkmcnt(0)" ::: "memory");

        // ---- phase 2: per-channel dot + BN via 4 FMAs, 2-wide with v_max3/v_min3 ----
        float vmaxA = -INFINITY, vminA = INFINITY;
        {
            const float4* la = &lds[wid][0];
            int m = 0;
            for (; m + 2 <= nA; m += 2) {
                float4 t0 = la[m];      // broadcast reads: all lanes same address, no conflict
                float4 t1 = la[m+1];
                float y0 = fmaf(t0.x, A0, fmaf(t0.y, A1, fmaf(t0.z, A2, fmaf(t0.w, A3, CA))));
                float y1 = fmaf(t1.x, A0, fmaf(t1.y, A1, fmaf(t1.z, A2, fmaf(t1.w, A3, CA))));
                vmaxA = max3f(vmaxA, y0, y1);
                vminA = min3f(vminA, y0, y1);
            }
            if (m < nA) {
                float4 t = la[m];
                float y = fmaf(t.x, A0, fmaf(t.y, A1, fmaf(t.z, A2, fmaf(t.w, A3, CA))));
                vmaxA = fmaxf(vmaxA, y);
                vminA = fminf(vminA, y);
            }
        }
        float vmaxB = -INFINITY, vminB = INFINITY;
        {
            const float4* lb = &lds[wid][32];
            int m = 0;
            for (; m + 2 <= nB; m += 2) {
                float4 t0 = lb[m];
                float4 t1 = lb[m+1];
                float y0 = fmaf(t0.x, A0, fmaf(t0.y, A1, fmaf(t0.z, A2, fmaf(t0.w, A3, CB))));
                float y1 = fmaf(t1.x, A0, fmaf(t1.y, A1, fmaf(t1.z, A2, fmaf(t1.w, A3, CB))));
                vmaxB = max3f(vmaxB, y0, y1);
                vminB = min3f(vminB, y0, y1);
            }
            if (m < nB) {
                float4 t = lb[m];
                float y = fmaf(t.x, A0, fmaf(t.y, A1, fmaf(t.z, A2, fmaf(t.w, A3, CB))));
                vmaxB = fmaxf(vmaxB, y);
                vminB = fminf(vminB, y);
            }
        }
        if (nA < 32) { vmaxA = fmaxf(vmaxA, b); vminA = fminf(vminA, b); }
        if (nB < 32) { vmaxB = fmaxf(vmaxB, b); vminB = fminf(vminB, b); }

        // valley property: max over set attained at min or max pre-activation
        const float rAo = fmaxf(gelu_exact(vmaxA), gelu_exact(vminA));
        const float rBo = fmaxf(gelu_exact(vmaxB), gelu_exact(vminB));

        out[(size_t)iA * 64 + o] = rAo;
        if (hasB) out[(size_t)iB * 64 + o] = rBo;
    }
}

extern "C" void kernel_launch(void* const* d_in, const int* in_sizes, int n_in,
                              void* d_out, int out_size, void* d_ws, size_t ws_size,
                              hipStream_t stream) {
    const float* features   = (const float*)d_in[0];
    const int*   num_points = (const int*)  d_in[1];
    const int*   coors      = (const int*)  d_in[2];
    const float* W          = (const float*)d_in[3];
    const float* gamma      = (const float*)d_in[4];
    const float* beta       = (const float*)d_in[5];
    const float* rmean      = (const float*)d_in[6];
    const float* rvar       = (const float*)d_in[7];
    float* out = (float*)d_out;

    const int nTotal = in_sizes[1];  // N pillars

    // 2 pairs per wave: fine-grained blocks let the HW scheduler backfill (tail balance).
    const int nPairs = (nTotal + 1) / 2;
    int blocks = (nPairs + 7) / 8;   // 4 waves/block x 2 pairs/wave
    if (blocks < 1) blocks = 1;
    pfn_kernel<<<blocks, 256, 0, stream>>>(features, num_points, coors, W,
                                           gamma, beta, rmean, rvar, out, nTotal);
}